// Round 1
// baseline (111.390 us; speedup 1.0000x reference)
//
#include <hip/hip_runtime.h>

#define N 64
#define NPAD 65          // +1 pad: LDS bank = (row+col)%32 -> 2-way alias only (free)
#define ITERS 50
#define TEMP 12.5f
#define WEPS 1e-5f
#define QDIM 75
#define WDIM 5

__device__ __forceinline__ float waveReduceSum(float x) {
#pragma unroll
    for (int off = 32; off; off >>= 1) x += __shfl_xor(x, off, 64);
    return x;
}

__global__ __launch_bounds__(64) void emd_sinkhorn_kernel(
    const float* __restrict__ sim,   // [B, 64, 64]
    const float* __restrict__ w1,    // [E, Q, W, N] == [B, N]
    const float* __restrict__ w2,    // [E, W, Q, N]  (note transposed Q/W)
    float* __restrict__ out,         // [B]
    int B)
{
    __shared__ __align__(16) float S[N * NPAD];   // sim matrix, padded rows
    __shared__ __align__(16) float U[N];
    __shared__ __align__(16) float V[N];

    const int b    = blockIdx.x;
    const int lane = threadIdx.x;   // single wave per block
    const float* g = sim + (size_t)b * N * N;

    // ---- stage sim into padded LDS, coalesced float4 global loads ----
    const float4* g4 = (const float4*)g;
#pragma unroll
    for (int t = 0; t < 16; ++t) {
        float4 x = g4[t * 64 + lane];
        int e0 = (t * 64 + lane) * 4;
        int r = e0 >> 6;            // = 4t + (lane>>4)
        int c = e0 & 63;            // = (lane&15)*4
        S[r * NPAD + c + 0] = x.x;
        S[r * NPAD + c + 1] = x.y;
        S[r * NPAD + c + 2] = x.z;
        S[r * NPAD + c + 3] = x.w;
    }
    __syncthreads();

    // ---- K row (lane = row index) and K col (lane = col index) in registers ----
    // K = exp(-cost/eps) = exp(20*(sim-1))
    float Krow[N], Kcol[N];
#pragma unroll
    for (int j = 0; j < N; ++j)
        Krow[j] = __expf((S[lane * NPAD + j] - 1.0f) * 20.0f);
#pragma unroll
    for (int i = 0; i < N; ++i)
        Kcol[i] = __expf((S[i * NPAD + lane] - 1.0f) * 20.0f);

    // ---- marginals: relu + eps, renormalize to sum N ----
    float a = w1[(size_t)b * N + lane];
    a = fmaxf(a, 0.0f) + WEPS;
    a *= (float)N / waveReduceSum(a);

    const int e   = b / (QDIM * WDIM);
    const int rem = b % (QDIM * WDIM);
    const int q   = rem / WDIM;
    const int w   = rem % WDIM;
    float bb = w2[((((size_t)e * WDIM + w) * QDIM) + q) * N + lane];
    bb = fmaxf(bb, 0.0f) + WEPS;
    bb *= (float)N / waveReduceSum(bb);

    V[lane] = 1.0f;   // log_v = 0 init
    __syncthreads();

    float u = 0.0f, v = 1.0f;
#pragma unroll 1
    for (int it = 0; it < ITERS; ++it) {
        // u = a / (K v)   -- row matvec from registers, v broadcast from LDS
        const float4* V4 = (const float4*)V;
        float acc0 = 0, acc1 = 0, acc2 = 0, acc3 = 0;
#pragma unroll
        for (int j4 = 0; j4 < 16; ++j4) {
            float4 vv = V4[j4];                         // uniform addr -> broadcast
            acc0 = fmaf(Krow[4 * j4 + 0], vv.x, acc0);
            acc1 = fmaf(Krow[4 * j4 + 1], vv.y, acc1);
            acc2 = fmaf(Krow[4 * j4 + 2], vv.z, acc2);
            acc3 = fmaf(Krow[4 * j4 + 3], vv.w, acc3);
        }
        u = a * __builtin_amdgcn_rcpf((acc0 + acc1) + (acc2 + acc3));
        U[lane] = u;
        __syncthreads();

        // v = b / (K^T u) -- col matvec from registers, u broadcast from LDS
        const float4* U4 = (const float4*)U;
        acc0 = 0; acc1 = 0; acc2 = 0; acc3 = 0;
#pragma unroll
        for (int i4 = 0; i4 < 16; ++i4) {
            float4 uu = U4[i4];
            acc0 = fmaf(Kcol[4 * i4 + 0], uu.x, acc0);
            acc1 = fmaf(Kcol[4 * i4 + 1], uu.y, acc1);
            acc2 = fmaf(Kcol[4 * i4 + 2], uu.z, acc2);
            acc3 = fmaf(Kcol[4 * i4 + 3], uu.w, acc3);
        }
        v = bb * __builtin_amdgcn_rcpf((acc0 + acc1) + (acc2 + acc3));
        V[lane] = v;
        __syncthreads();
    }

    // ---- score = sum_ij u_i K_ij v_j sim_ij ----
    float s0 = 0, s1 = 0, s2 = 0, s3 = 0;
#pragma unroll
    for (int j4 = 0; j4 < 16; ++j4) {
        float4 vv = ((const float4*)V)[j4];
        s0 = fmaf(Krow[4 * j4 + 0] * S[lane * NPAD + 4 * j4 + 0], vv.x, s0);
        s1 = fmaf(Krow[4 * j4 + 1] * S[lane * NPAD + 4 * j4 + 1], vv.y, s1);
        s2 = fmaf(Krow[4 * j4 + 2] * S[lane * NPAD + 4 * j4 + 2], vv.z, s2);
        s3 = fmaf(Krow[4 * j4 + 3] * S[lane * NPAD + 4 * j4 + 3], vv.w, s3);
    }
    float partial = u * ((s0 + s1) + (s2 + s3));
    float tot = waveReduceSum(partial);
    if (lane == 0) out[b] = tot * (TEMP / (float)N);
}

extern "C" void kernel_launch(void* const* d_in, const int* in_sizes, int n_in,
                              void* d_out, int out_size, void* d_ws, size_t ws_size,
                              hipStream_t stream) {
    const float* sim = (const float*)d_in[0];
    const float* w1  = (const float*)d_in[1];
    const float* w2  = (const float*)d_in[2];
    float* out       = (float*)d_out;
    const int B = in_sizes[0] / (N * N);   // 1500
    emd_sinkhorn_kernel<<<B, 64, 0, stream>>>(sim, w1, w2, out, B);
}